// Round 3
// baseline (792.694 us; speedup 1.0000x reference)
//
#include <hip/hip_runtime.h>

#define N_NODES 50000
#define N_EDGES 800000
#define E_TOT   (N_EDGES + N_NODES)
#define NUM_GRAPHS 64
#define NB_SCAN ((N_NODES + 1023) / 1024)   // 49 scan blocks

// ---------------- init: deg=1 (self loop), gsum/gcnt=0 ----------------
__global__ void k_init(int* __restrict__ deg, int* __restrict__ gz) {
    int i = blockIdx.x * blockDim.x + threadIdx.x;
    if (i < N_NODES) deg[i] = 1;
    if (i < NUM_GRAPHS * 32 + 64) gz[i] = 0;
}

// ---------------- degree histogram ----------------
__global__ void k_deg(const int* __restrict__ dst, int* __restrict__ deg) {
    int e = blockIdx.x * blockDim.x + threadIdx.x;
    if (e < N_EDGES) atomicAdd(&deg[dst[e]], 1);
}

// ---------------- 3-phase exclusive scan over deg -> row_start ----------------
__global__ __launch_bounds__(1024) void k_scan1(const int* __restrict__ deg,
                                                int* __restrict__ rs,
                                                int* __restrict__ bsum) {
    __shared__ int tmp[1024];
    int tid = threadIdx.x;
    int i = blockIdx.x * 1024 + tid;
    int v = (i < N_NODES) ? deg[i] : 0;
    tmp[tid] = v;
    __syncthreads();
    for (int off = 1; off < 1024; off <<= 1) {
        int add = (tid >= off) ? tmp[tid - off] : 0;
        __syncthreads();
        tmp[tid] += add;
        __syncthreads();
    }
    if (i < N_NODES) rs[i] = tmp[tid] - v;     // block-local exclusive
    if (tid == 1023) bsum[blockIdx.x] = tmp[1023];
}

__global__ void k_scan2(int* __restrict__ bsum) {
    int lane = threadIdx.x;                    // single wave of 64
    int v = (lane < NB_SCAN) ? bsum[lane] : 0;
    int inc = v;
    #pragma unroll
    for (int off = 1; off < 64; off <<= 1) {
        int u = __shfl_up(inc, off, 64);
        if (lane >= off) inc += u;
    }
    if (lane < NB_SCAN) bsum[lane] = inc - v;  // exclusive block offsets
}

__global__ __launch_bounds__(1024) void k_scan3(int* __restrict__ rs,
                                                const int* __restrict__ bsum,
                                                int* __restrict__ cursor,
                                                const int* __restrict__ deg,
                                                float* __restrict__ dinv) {
    int i = blockIdx.x * 1024 + threadIdx.x;
    if (i < N_NODES) {
        int r = rs[i] + bsum[blockIdx.x];
        rs[i] = r;
        cursor[i] = r;
        dinv[i] = rsqrtf((float)deg[i]);
    }
    if (i == 0) rs[N_NODES] = E_TOT;           // total is a compile-time constant
}

// ---------------- CSR scatter (edges + self loops) ----------------
__global__ void k_scatter(const int* __restrict__ ei, int* __restrict__ cursor,
                          int* __restrict__ csr) {
    int e = blockIdx.x * blockDim.x + threadIdx.x;
    if (e >= E_TOT) return;
    int s, d;
    if (e < N_EDGES) { s = ei[e]; d = ei[N_EDGES + e]; }
    else             { s = e - N_EDGES; d = s; }
    int p = atomicAdd(&cursor[d], 1);
    csr[p] = s;
}

// ---------------- GEMM: H[n, c0..c0+MT) = (X @ W)[n] * dinv[n] ----------------
template <int K, int M, int MT, int FTH, int NTH, int NT>
__global__ __launch_bounds__(FTH * NTH)
void k_gemm(const float* __restrict__ X, const float* __restrict__ W,
            const float* __restrict__ dinv, float* __restrict__ H) {
    constexpr int NODES = NTH * NT;
    constexpr int BLOCK = FTH * NTH;
    __shared__ float ws[K * MT];
    __shared__ float xs[K * NODES];            // xs[k*NODES + n] (transposed)
    const int tid = threadIdx.x;
    const int n0 = blockIdx.x * NODES;
    const int c0 = blockIdx.y * MT;

    for (int i = tid; i < K * MT / 4; i += BLOCK) {
        int k = i / (MT / 4), cv = i % (MT / 4);
        *(float4*)&ws[k * MT + cv * 4] = *(const float4*)&W[k * M + c0 + cv * 4];
    }
    constexpr int KV = K / 4;
    for (int i = tid; i < NODES * KV; i += BLOCK) {
        int r = i / KV, kv = i % KV;
        int node = n0 + r;
        float4 v = make_float4(0.f, 0.f, 0.f, 0.f);
        if (node < N_NODES) v = *(const float4*)&X[(size_t)node * K + kv * 4];
        xs[(kv * 4 + 0) * NODES + r] = v.x;
        xs[(kv * 4 + 1) * NODES + r] = v.y;
        xs[(kv * 4 + 2) * NODES + r] = v.z;
        xs[(kv * 4 + 3) * NODES + r] = v.w;
    }
    __syncthreads();

    const int ft = tid % FTH;
    const int nt = tid / FTH;
    float acc[NT][4];
    #pragma unroll
    for (int i = 0; i < NT; ++i) { acc[i][0] = acc[i][1] = acc[i][2] = acc[i][3] = 0.f; }

    #pragma unroll 4
    for (int k = 0; k < K; ++k) {
        float4 w = *(const float4*)&ws[k * MT + ft * 4];
        float4 xv = *(const float4*)&xs[k * NODES + nt * NT];
        float xa[4] = {xv.x, xv.y, xv.z, xv.w};
        #pragma unroll
        for (int j = 0; j < NT; ++j) {
            acc[j][0] += xa[j] * w.x;
            acc[j][1] += xa[j] * w.y;
            acc[j][2] += xa[j] * w.z;
            acc[j][3] += xa[j] * w.w;
        }
    }
    #pragma unroll
    for (int i = 0; i < NT; ++i) {
        int node = n0 + nt * NT + i;
        if (node < N_NODES) {
            float s = dinv[node];
            float4 o = make_float4(acc[i][0] * s, acc[i][1] * s, acc[i][2] * s, acc[i][3] * s);
            *(float4*)&H[(size_t)node * M + c0 + ft * 4] = o;
        }
    }
}

// ---------------- pull aggregation, wave-cooperative ----------------
// One wave per (node, feature-slice). Lane = edge_slot * CH + chunk:
// each gather instruction reads EP=64/CH DISTINCT rows simultaneously ->
// hardware-guaranteed EP-way memory-level parallelism per instruction
// (round-2 lesson: per-thread unrolling gets re-serialized by the register
// allocator; in-instruction lane parallelism cannot be).
// Edge-slot reduction = shfl_xor butterfly, store/epilogue on lanes ew==0.
template <int F, int CH, bool POOL>
__global__ __launch_bounds__(256)
void k_agg(const float* __restrict__ H, const int* __restrict__ rs,
           const int* __restrict__ csr, const float* __restrict__ dinv,
           const float* __restrict__ bias, float* __restrict__ OUT,
           const int* __restrict__ batch, float* __restrict__ gsum,
           int* __restrict__ gcnt) {
    constexpr int EP = 64 / CH;                 // edge slots per wave
    const int lane = threadIdx.x & 63;
    const int wid  = threadIdx.x >> 6;
    const int node = blockIdx.x * 4 + wid;
    if (node >= N_NODES) return;
    const int c  = lane & (CH - 1);             // chunk (float4) within slice
    const int ew = lane / CH;                   // edge slot
    const int fbase = blockIdx.y * CH * 4 + c * 4;

    const int e0 = rs[node], e1 = rs[node + 1];
    float4 acc = make_float4(0.f, 0.f, 0.f, 0.f);
    for (int e = e0 + ew; e < e1; e += EP) {
        int s = csr[e];
        float4 v = *(const float4*)&H[(size_t)s * F + fbase];
        acc.x += v.x; acc.y += v.y; acc.z += v.z; acc.w += v.w;
    }
    // butterfly reduce over edge-slot bits (CH..32)
    #pragma unroll
    for (int m = CH; m < 64; m <<= 1) {
        acc.x += __shfl_xor(acc.x, m, 64);
        acc.y += __shfl_xor(acc.y, m, 64);
        acc.z += __shfl_xor(acc.z, m, 64);
        acc.w += __shfl_xor(acc.w, m, 64);
    }
    if (ew == 0) {
        float d = dinv[node];
        float4 b = *(const float4*)&bias[fbase];
        float ox = fmaxf(acc.x * d + b.x, 0.f);
        float oy = fmaxf(acc.y * d + b.y, 0.f);
        float oz = fmaxf(acc.z * d + b.z, 0.f);
        float ow = fmaxf(acc.w * d + b.w, 0.f);
        if constexpr (POOL) {
            int g = batch[node];
            atomicAdd(&gsum[g * F + fbase + 0], ox);
            atomicAdd(&gsum[g * F + fbase + 1], oy);
            atomicAdd(&gsum[g * F + fbase + 2], oz);
            atomicAdd(&gsum[g * F + fbase + 3], ow);
            if (c == 0 && blockIdx.y == 0) atomicAdd(&gcnt[g], 1);
        } else {
            *(float4*)&OUT[(size_t)node * F + fbase] = make_float4(ox, oy, oz, ow);
        }
    }
}

__global__ void k_final(const float* __restrict__ gsum, const int* __restrict__ gcnt,
                        float* __restrict__ out) {
    int t = blockIdx.x * blockDim.x + threadIdx.x;
    if (t < NUM_GRAPHS * 32) {
        int g = t / 32;
        float c = fmaxf((float)gcnt[g], 1.0f);
        out[t] = gsum[t] / c;
    }
}

extern "C" void kernel_launch(void* const* d_in, const int* in_sizes, int n_in,
                              void* d_out, int out_size, void* d_ws, size_t ws_size,
                              hipStream_t stream) {
    const float* x     = (const float*)d_in[0];
    const int*   ei    = (const int*)d_in[1];
    const int*   batch = (const int*)d_in[2];
    const float* W1    = (const float*)d_in[3];
    const float* b1    = (const float*)d_in[4];
    const float* W2    = (const float*)d_in[5];
    const float* b2    = (const float*)d_in[6];
    const float* W3    = (const float*)d_in[7];
    const float* b3    = (const float*)d_in[8];
    float* out = (float*)d_out;

    char* ws = (char*)d_ws;
    size_t o = 0;
    auto alloc = [&](size_t bytes) {
        char* p = ws + o;
        o = (o + bytes + 255) & ~(size_t)255;
        return p;
    };
    float* bufA = (float*)alloc((size_t)N_NODES * 96 * 4);
    float* bufB = (float*)alloc((size_t)N_NODES * 96 * 4);
    int*   deg    = (int*)alloc((size_t)N_NODES * 4);
    float* dinv   = (float*)alloc((size_t)N_NODES * 4);
    int*   rs     = (int*)alloc((size_t)(N_NODES + 1) * 4);
    int*   cursor = (int*)alloc((size_t)N_NODES * 4);
    int*   csr    = (int*)alloc((size_t)E_TOT * 4);
    int*   bsum   = (int*)alloc(64 * 4);
    float* gsum   = (float*)alloc((size_t)NUM_GRAPHS * 32 * 4 + 64 * 4);
    int*   gcnt   = (int*)(gsum + NUM_GRAPHS * 32);

    // build normalization + CSR (by dst)
    hipLaunchKernelGGL(k_init, dim3((N_NODES + 255) / 256), dim3(256), 0, stream, deg, (int*)gsum);
    hipLaunchKernelGGL(k_deg, dim3((N_EDGES + 255) / 256), dim3(256), 0, stream, ei + N_EDGES, deg);
    hipLaunchKernelGGL(k_scan1, dim3(NB_SCAN), dim3(1024), 0, stream, deg, rs, bsum);
    hipLaunchKernelGGL(k_scan2, dim3(1), dim3(64), 0, stream, bsum);
    hipLaunchKernelGGL(k_scan3, dim3(NB_SCAN), dim3(1024), 0, stream, rs, bsum, cursor, deg, dinv);
    hipLaunchKernelGGL(k_scatter, dim3((E_TOT + 255) / 256), dim3(256), 0, stream, ei, cursor, csr);

    // layer 1: K=128 -> M=96
    hipLaunchKernelGGL((k_gemm<128, 96, 48, 12, 16, 4>), dim3((N_NODES + 63) / 64, 2), dim3(192), 0, stream,
                       x, W1, dinv, bufA);
    hipLaunchKernelGGL((k_agg<96, 8, false>), dim3((N_NODES + 3) / 4, 3), dim3(256), 0, stream,
                       bufA, rs, csr, dinv, b1, bufB, nullptr, nullptr, nullptr);
    // layer 2: K=96 -> M=48
    hipLaunchKernelGGL((k_gemm<96, 48, 48, 12, 16, 4>), dim3((N_NODES + 63) / 64, 1), dim3(192), 0, stream,
                       bufB, W2, dinv, bufA);
    hipLaunchKernelGGL((k_agg<48, 4, false>), dim3((N_NODES + 3) / 4, 3), dim3(256), 0, stream,
                       bufA, rs, csr, dinv, b2, bufB, nullptr, nullptr, nullptr);
    // layer 3: K=48 -> M=32, aggregation fused with mean-pool accumulation
    hipLaunchKernelGGL((k_gemm<48, 32, 32, 8, 24, 4>), dim3((N_NODES + 95) / 96, 1), dim3(192), 0, stream,
                       bufB, W3, dinv, bufA);
    hipLaunchKernelGGL((k_agg<32, 8, true>), dim3((N_NODES + 3) / 4, 1), dim3(256), 0, stream,
                       bufA, rs, csr, dinv, b3, nullptr, batch, gsum, gcnt);
    hipLaunchKernelGGL(k_final, dim3((NUM_GRAPHS * 32 + 255) / 256), dim3(256), 0, stream, gsum, gcnt, out);
}

// Round 4
// 580.022 us; speedup vs baseline: 1.3667x; 1.3667x over previous
//
#include <hip/hip_runtime.h>

#define N_NODES 50000
#define N_EDGES 800000
#define E_TOT   (N_EDGES + N_NODES)
#define NUM_GRAPHS 64
#define NB_SCAN ((N_NODES + 1023) / 1024)   // 49 scan blocks

__device__ __forceinline__ float bf_lo(unsigned u) { return __uint_as_float(u << 16); }
__device__ __forceinline__ float bf_hi(unsigned u) { return __uint_as_float(u & 0xffff0000u); }
__device__ __forceinline__ unsigned short f2bf(float f) {           // RNE
    unsigned u = __float_as_uint(f);
    return (unsigned short)((u + 0x7fffu + ((u >> 16) & 1u)) >> 16);
}

// ---------------- init: deg=1 (self loop), gsum/gcnt=0 ----------------
__global__ void k_init(int* __restrict__ deg, int* __restrict__ gz) {
    int i = blockIdx.x * blockDim.x + threadIdx.x;
    if (i < N_NODES) deg[i] = 1;
    if (i < NUM_GRAPHS * 32 + 64) gz[i] = 0;
}

// ---------------- degree histogram ----------------
__global__ void k_deg(const int* __restrict__ dst, int* __restrict__ deg) {
    int e = blockIdx.x * blockDim.x + threadIdx.x;
    if (e < N_EDGES) atomicAdd(&deg[dst[e]], 1);
}

// ---------------- 3-phase exclusive scan over deg -> row_start ----------------
__global__ __launch_bounds__(1024) void k_scan1(const int* __restrict__ deg,
                                                int* __restrict__ rs,
                                                int* __restrict__ bsum) {
    __shared__ int tmp[1024];
    int tid = threadIdx.x;
    int i = blockIdx.x * 1024 + tid;
    int v = (i < N_NODES) ? deg[i] : 0;
    tmp[tid] = v;
    __syncthreads();
    for (int off = 1; off < 1024; off <<= 1) {
        int add = (tid >= off) ? tmp[tid - off] : 0;
        __syncthreads();
        tmp[tid] += add;
        __syncthreads();
    }
    if (i < N_NODES) rs[i] = tmp[tid] - v;     // block-local exclusive
    if (tid == 1023) bsum[blockIdx.x] = tmp[1023];
}

__global__ void k_scan2(int* __restrict__ bsum) {
    int lane = threadIdx.x;                    // single wave of 64
    int v = (lane < NB_SCAN) ? bsum[lane] : 0;
    int inc = v;
    #pragma unroll
    for (int off = 1; off < 64; off <<= 1) {
        int u = __shfl_up(inc, off, 64);
        if (lane >= off) inc += u;
    }
    if (lane < NB_SCAN) bsum[lane] = inc - v;  // exclusive block offsets
}

__global__ __launch_bounds__(1024) void k_scan3(int* __restrict__ rs,
                                                const int* __restrict__ bsum,
                                                int* __restrict__ cursor,
                                                const int* __restrict__ deg,
                                                float* __restrict__ dinv) {
    int i = blockIdx.x * 1024 + threadIdx.x;
    if (i < N_NODES) {
        int r = rs[i] + bsum[blockIdx.x];
        rs[i] = r;
        cursor[i] = r;
        dinv[i] = rsqrtf((float)deg[i]);
    }
    if (i == 0) rs[N_NODES] = E_TOT;           // total is a compile-time constant
}

// ---------------- CSR scatter (edges + self loops) ----------------
__global__ void k_scatter(const int* __restrict__ ei, int* __restrict__ cursor,
                          int* __restrict__ csr) {
    int e = blockIdx.x * blockDim.x + threadIdx.x;
    if (e >= E_TOT) return;
    int s, d;
    if (e < N_EDGES) { s = ei[e]; d = ei[N_EDGES + e]; }
    else             { s = e - N_EDGES; d = s; }
    int p = atomicAdd(&cursor[d], 1);
    csr[p] = s;
}

// ---------------- GEMM: H[n, :] = (X @ W)[n] * dinv[n], optional bf16 out ----
template <int K, int M, int MT, int FTH, int NTH, int NT, int OSTRIDE, bool BF16OUT>
__global__ __launch_bounds__(FTH * NTH)
void k_gemm(const float* __restrict__ X, const float* __restrict__ W,
            const float* __restrict__ dinv, void* __restrict__ Hv) {
    constexpr int NODES = NTH * NT;
    constexpr int BLOCK = FTH * NTH;
    __shared__ float ws[K * MT];
    __shared__ float xs[K * NODES];            // xs[k*NODES + n] (transposed)
    const int tid = threadIdx.x;
    const int n0 = blockIdx.x * NODES;
    const int c0 = blockIdx.y * MT;

    for (int i = tid; i < K * MT / 4; i += BLOCK) {
        int k = i / (MT / 4), cv = i % (MT / 4);
        *(float4*)&ws[k * MT + cv * 4] = *(const float4*)&W[k * M + c0 + cv * 4];
    }
    constexpr int KV = K / 4;
    for (int i = tid; i < NODES * KV; i += BLOCK) {
        int r = i / KV, kv = i % KV;
        int node = n0 + r;
        float4 v = make_float4(0.f, 0.f, 0.f, 0.f);
        if (node < N_NODES) v = *(const float4*)&X[(size_t)node * K + kv * 4];
        xs[(kv * 4 + 0) * NODES + r] = v.x;
        xs[(kv * 4 + 1) * NODES + r] = v.y;
        xs[(kv * 4 + 2) * NODES + r] = v.z;
        xs[(kv * 4 + 3) * NODES + r] = v.w;
    }
    __syncthreads();

    const int ft = tid % FTH;
    const int nt = tid / FTH;
    float acc[NT][4];
    #pragma unroll
    for (int i = 0; i < NT; ++i) { acc[i][0] = acc[i][1] = acc[i][2] = acc[i][3] = 0.f; }

    #pragma unroll 4
    for (int k = 0; k < K; ++k) {
        float4 w = *(const float4*)&ws[k * MT + ft * 4];
        float4 xv = *(const float4*)&xs[k * NODES + nt * NT];
        float xa[4] = {xv.x, xv.y, xv.z, xv.w};
        #pragma unroll
        for (int j = 0; j < NT; ++j) {
            acc[j][0] += xa[j] * w.x;
            acc[j][1] += xa[j] * w.y;
            acc[j][2] += xa[j] * w.z;
            acc[j][3] += xa[j] * w.w;
        }
    }
    #pragma unroll
    for (int i = 0; i < NT; ++i) {
        int node = n0 + nt * NT + i;
        if (node < N_NODES) {
            float s = dinv[node];
            float v0 = acc[i][0] * s, v1 = acc[i][1] * s, v2 = acc[i][2] * s, v3 = acc[i][3] * s;
            if constexpr (BF16OUT) {
                unsigned short* H = (unsigned short*)Hv;
                ushort4 o;
                o.x = f2bf(v0); o.y = f2bf(v1); o.z = f2bf(v2); o.w = f2bf(v3);
                *(ushort4*)&H[(size_t)node * OSTRIDE + c0 + ft * 4] = o;
            } else {
                float* H = (float*)Hv;
                *(float4*)&H[(size_t)node * OSTRIDE + c0 + ft * 4] = make_float4(v0, v1, v2, v3);
            }
        }
    }
}

// ---------------- pull aggregation from bf16 H (halved cache-line traffic) ---
// Per-thread chunk of 8 bf16 (one 16B uint4 gather). Gather is MSHR/L3-latency
// bound (~20 G-lines/s ceiling measured r1-r3); bf16 halves lines per row.
template <int F, int STRIDE>
__global__ void k_agg_bf(const unsigned short* __restrict__ H, const int* __restrict__ rs,
                         const int* __restrict__ csr, const float* __restrict__ dinv,
                         const float* __restrict__ bias, float* __restrict__ OUT) {
    constexpr int FV = F / 8;
    int t = blockIdx.x * blockDim.x + threadIdx.x;
    int node = t / FV, c = t % FV;
    if (node >= N_NODES) return;
    int e0 = rs[node], e1 = rs[node + 1];
    const unsigned short* Hc = H + c * 8;
    float a0 = 0.f, a1 = 0.f, a2 = 0.f, a3 = 0.f, a4 = 0.f, a5 = 0.f, a6 = 0.f, a7 = 0.f;
    for (int e = e0; e < e1; ++e) {
        int s = csr[e];
        uint4 v = *(const uint4*)(Hc + (size_t)s * STRIDE);
        a0 += bf_lo(v.x); a1 += bf_hi(v.x);
        a2 += bf_lo(v.y); a3 += bf_hi(v.y);
        a4 += bf_lo(v.z); a5 += bf_hi(v.z);
        a6 += bf_lo(v.w); a7 += bf_hi(v.w);
    }
    float d = dinv[node];
    const float4* bp = (const float4*)(bias + c * 8);
    float4 b0 = bp[0], b1 = bp[1];
    float4 o0, o1;
    o0.x = fmaxf(a0 * d + b0.x, 0.f); o0.y = fmaxf(a1 * d + b0.y, 0.f);
    o0.z = fmaxf(a2 * d + b0.z, 0.f); o0.w = fmaxf(a3 * d + b0.w, 0.f);
    o1.x = fmaxf(a4 * d + b1.x, 0.f); o1.y = fmaxf(a5 * d + b1.y, 0.f);
    o1.z = fmaxf(a6 * d + b1.z, 0.f); o1.w = fmaxf(a7 * d + b1.w, 0.f);
    float* op = OUT + (size_t)node * F + c * 8;
    *(float4*)op = o0;
    *(float4*)(op + 4) = o1;
}

// ---------------- fp32 pull aggregation (layer 3) + fused mean-pool ----------
template <int F, bool POOL>
__global__ void k_agg(const float* __restrict__ H, const int* __restrict__ rs,
                      const int* __restrict__ csr, const float* __restrict__ dinv,
                      const float* __restrict__ bias, float* __restrict__ OUT,
                      const int* __restrict__ batch, float* __restrict__ gsum,
                      int* __restrict__ gcnt) {
    constexpr int FV = F / 4;
    int t = blockIdx.x * blockDim.x + threadIdx.x;
    int node = t / FV, c = t % FV;
    if (node >= N_NODES) return;
    int e0 = rs[node], e1 = rs[node + 1];
    const float* Hc = H + (size_t)c * 4;
    float ax = 0.f, ay = 0.f, az = 0.f, aw = 0.f;
    for (int e = e0; e < e1; ++e) {
        int s = csr[e];
        float4 v = *(const float4*)&Hc[(size_t)s * F];
        ax += v.x; ay += v.y; az += v.z; aw += v.w;
    }
    float d = dinv[node];
    float4 b = *(const float4*)&bias[c * 4];
    float ox = fmaxf(ax * d + b.x, 0.f);
    float oy = fmaxf(ay * d + b.y, 0.f);
    float oz = fmaxf(az * d + b.z, 0.f);
    float ow = fmaxf(aw * d + b.w, 0.f);
    if constexpr (POOL) {
        int g = batch[node];
        atomicAdd(&gsum[g * F + c * 4 + 0], ox);
        atomicAdd(&gsum[g * F + c * 4 + 1], oy);
        atomicAdd(&gsum[g * F + c * 4 + 2], oz);
        atomicAdd(&gsum[g * F + c * 4 + 3], ow);
        if (c == 0) atomicAdd(&gcnt[g], 1);
    } else {
        *(float4*)&OUT[(size_t)node * F + c * 4] = make_float4(ox, oy, oz, ow);
    }
}

__global__ void k_final(const float* __restrict__ gsum, const int* __restrict__ gcnt,
                        float* __restrict__ out) {
    int t = blockIdx.x * blockDim.x + threadIdx.x;
    if (t < NUM_GRAPHS * 32) {
        int g = t / 32;
        float c = fmaxf((float)gcnt[g], 1.0f);
        out[t] = gsum[t] / c;
    }
}

extern "C" void kernel_launch(void* const* d_in, const int* in_sizes, int n_in,
                              void* d_out, int out_size, void* d_ws, size_t ws_size,
                              hipStream_t stream) {
    const float* x     = (const float*)d_in[0];
    const int*   ei    = (const int*)d_in[1];
    const int*   batch = (const int*)d_in[2];
    const float* W1    = (const float*)d_in[3];
    const float* b1    = (const float*)d_in[4];
    const float* W2    = (const float*)d_in[5];
    const float* b2    = (const float*)d_in[6];
    const float* W3    = (const float*)d_in[7];
    const float* b3    = (const float*)d_in[8];
    float* out = (float*)d_out;

    char* ws = (char*)d_ws;
    size_t o = 0;
    auto alloc = [&](size_t bytes) {
        char* p = ws + o;
        o = (o + bytes + 255) & ~(size_t)255;
        return p;
    };
    // P1: fp32 OUT1 [50000x96]; P2: bf16 H1 [50000x96] / fp32 OUT2 [50000x48];
    // P3: bf16 H2 [50000x64 padded] / fp32 H3 [50000x32]  (lifetimes disjoint)
    float*          P1 = (float*)alloc((size_t)N_NODES * 96 * 4);
    char*           P2 = (char*) alloc((size_t)N_NODES * 96 * 4 > (size_t)N_NODES * 48 * 4
                                       ? (size_t)N_NODES * 96 * 2 : (size_t)N_NODES * 48 * 4); // 9.6MB
    char*           P3 = (char*) alloc((size_t)N_NODES * 64 * 2);                              // 6.4MB
    int*   deg    = (int*)alloc((size_t)N_NODES * 4);
    float* dinv   = (float*)alloc((size_t)N_NODES * 4);
    int*   rs     = (int*)alloc((size_t)(N_NODES + 1) * 4);
    int*   cursor = (int*)alloc((size_t)N_NODES * 4);
    int*   csr    = (int*)alloc((size_t)E_TOT * 4);
    int*   bsum   = (int*)alloc(64 * 4);
    float* gsum   = (float*)alloc((size_t)NUM_GRAPHS * 32 * 4 + 64 * 4);
    int*   gcnt   = (int*)(gsum + NUM_GRAPHS * 32);

    unsigned short* H1 = (unsigned short*)P2;   // bf16, stride 96
    float*          O1 = P1;                    // fp32, stride 96
    unsigned short* H2 = (unsigned short*)P3;   // bf16, stride 64 (128B rows)
    float*          O2 = (float*)P2;            // fp32, stride 48
    float*          H3 = (float*)P3;            // fp32, stride 32

    // build normalization + CSR (by dst)
    hipLaunchKernelGGL(k_init, dim3((N_NODES + 255) / 256), dim3(256), 0, stream, deg, (int*)gsum);
    hipLaunchKernelGGL(k_deg, dim3((N_EDGES + 255) / 256), dim3(256), 0, stream, ei + N_EDGES, deg);
    hipLaunchKernelGGL(k_scan1, dim3(NB_SCAN), dim3(1024), 0, stream, deg, rs, bsum);
    hipLaunchKernelGGL(k_scan2, dim3(1), dim3(64), 0, stream, bsum);
    hipLaunchKernelGGL(k_scan3, dim3(NB_SCAN), dim3(1024), 0, stream, rs, bsum, cursor, deg, dinv);
    hipLaunchKernelGGL(k_scatter, dim3((E_TOT + 255) / 256), dim3(256), 0, stream, ei, cursor, csr);

    // layer 1: K=128 -> M=96, bf16 H
    hipLaunchKernelGGL((k_gemm<128, 96, 48, 12, 16, 4, 96, true>), dim3((N_NODES + 63) / 64, 2), dim3(192), 0, stream,
                       x, W1, dinv, H1);
    hipLaunchKernelGGL((k_agg_bf<96, 96>), dim3((N_NODES * 12 + 255) / 256), dim3(256), 0, stream,
                       H1, rs, csr, dinv, b1, O1);
    // layer 2: K=96 -> M=48, bf16 H padded to 64-elem rows (128B = 2 lines)
    hipLaunchKernelGGL((k_gemm<96, 48, 48, 12, 16, 4, 64, true>), dim3((N_NODES + 63) / 64, 1), dim3(192), 0, stream,
                       O1, W2, dinv, H2);
    hipLaunchKernelGGL((k_agg_bf<48, 64>), dim3((N_NODES * 6 + 255) / 256), dim3(256), 0, stream,
                       H2, rs, csr, dinv, b2, O2);
    // layer 3: K=48 -> M=32, fp32, aggregation fused with mean-pool accumulation
    hipLaunchKernelGGL((k_gemm<48, 32, 32, 8, 24, 4, 32, false>), dim3((N_NODES + 95) / 96, 1), dim3(192), 0, stream,
                       O2, W3, dinv, H3);
    hipLaunchKernelGGL((k_agg<32, true>), dim3((N_NODES * 8 + 255) / 256), dim3(256), 0, stream,
                       H3, rs, csr, dinv, b3, nullptr, batch, gsum, gcnt);
    hipLaunchKernelGGL(k_final, dim3((NUM_GRAPHS * 32 + 255) / 256), dim3(256), 0, stream, gsum, gcnt, out);
}

// Round 5
// 377.805 us; speedup vs baseline: 2.0982x; 1.5352x over previous
//
#include <hip/hip_runtime.h>

#define N_NODES 50000
#define N_EDGES 800000
#define E_TOT   (N_EDGES + N_NODES)
#define NUM_GRAPHS 64
#define NB_SCAN ((N_NODES + 1023) / 1024)   // 49 scan blocks

__device__ __forceinline__ float bf_lo(unsigned u) { return __uint_as_float(u << 16); }
__device__ __forceinline__ float bf_hi(unsigned u) { return __uint_as_float(u & 0xffff0000u); }
__device__ __forceinline__ unsigned short f2bf(float f) {           // RNE
    unsigned u = __float_as_uint(f);
    return (unsigned short)((u + 0x7fffu + ((u >> 16) & 1u)) >> 16);
}

// ---------------- init: deg=1 (self loop) ----------------
__global__ void k_init(int* __restrict__ deg) {
    int i = blockIdx.x * blockDim.x + threadIdx.x;
    if (i < N_NODES) deg[i] = 1;
}

// ---------------- degree histogram ----------------
__global__ void k_deg(const int* __restrict__ dst, int* __restrict__ deg) {
    int e = blockIdx.x * blockDim.x + threadIdx.x;
    if (e < N_EDGES) atomicAdd(&deg[dst[e]], 1);
}

// ---------------- 3-phase exclusive scan over deg -> row_start ----------------
__global__ __launch_bounds__(1024) void k_scan1(const int* __restrict__ deg,
                                                int* __restrict__ rs,
                                                int* __restrict__ bsum) {
    __shared__ int tmp[1024];
    int tid = threadIdx.x;
    int i = blockIdx.x * 1024 + tid;
    int v = (i < N_NODES) ? deg[i] : 0;
    tmp[tid] = v;
    __syncthreads();
    for (int off = 1; off < 1024; off <<= 1) {
        int add = (tid >= off) ? tmp[tid - off] : 0;
        __syncthreads();
        tmp[tid] += add;
        __syncthreads();
    }
    if (i < N_NODES) rs[i] = tmp[tid] - v;     // block-local exclusive
    if (tid == 1023) bsum[blockIdx.x] = tmp[1023];
}

__global__ void k_scan2(int* __restrict__ bsum) {
    int lane = threadIdx.x;                    // single wave of 64
    int v = (lane < NB_SCAN) ? bsum[lane] : 0;
    int inc = v;
    #pragma unroll
    for (int off = 1; off < 64; off <<= 1) {
        int u = __shfl_up(inc, off, 64);
        if (lane >= off) inc += u;
    }
    if (lane < NB_SCAN) bsum[lane] = inc - v;  // exclusive block offsets
}

__global__ __launch_bounds__(1024) void k_scan3(int* __restrict__ rs,
                                                const int* __restrict__ bsum,
                                                int* __restrict__ cursor,
                                                const int* __restrict__ deg,
                                                float* __restrict__ dinv) {
    int i = blockIdx.x * 1024 + threadIdx.x;
    if (i < N_NODES) {
        int r = rs[i] + bsum[blockIdx.x];
        rs[i] = r;
        cursor[i] = r;
        dinv[i] = rsqrtf((float)deg[i]);
    }
    if (i == 0) rs[N_NODES] = E_TOT;           // total is a compile-time constant
}

// ---------------- CSR scatter (edges + self loops) ----------------
__global__ void k_scatter(const int* __restrict__ ei, int* __restrict__ cursor,
                          int* __restrict__ csr) {
    int e = blockIdx.x * blockDim.x + threadIdx.x;
    if (e >= E_TOT) return;
    int s, d;
    if (e < N_EDGES) { s = ei[e]; d = ei[N_EDGES + e]; }
    else             { s = e - N_EDGES; d = s; }
    int p = atomicAdd(&cursor[d], 1);
    csr[p] = s;
}

// ---------------- graph boundaries: start[g] = lower_bound(batch, g) --------
__global__ void k_bounds(const int* __restrict__ batch, int* __restrict__ start) {
    int t = threadIdx.x;
    if (t > NUM_GRAPHS) return;
    int lo = 0, hi = N_NODES;
    while (lo < hi) {
        int mid = (lo + hi) >> 1;
        if (batch[mid] < t) lo = mid + 1; else hi = mid;
    }
    start[t] = lo;
}

// ---------------- GEMM: H[n, :] = (X @ W)[n] * dinv[n], optional bf16 out ----
template <int K, int M, int MT, int FTH, int NTH, int NT, int OSTRIDE, bool BF16OUT>
__global__ __launch_bounds__(FTH * NTH)
void k_gemm(const float* __restrict__ X, const float* __restrict__ W,
            const float* __restrict__ dinv, void* __restrict__ Hv) {
    constexpr int NODES = NTH * NT;
    constexpr int BLOCK = FTH * NTH;
    __shared__ float ws[K * MT];
    __shared__ float xs[K * NODES];            // xs[k*NODES + n] (transposed)
    const int tid = threadIdx.x;
    const int n0 = blockIdx.x * NODES;
    const int c0 = blockIdx.y * MT;

    for (int i = tid; i < K * MT / 4; i += BLOCK) {
        int k = i / (MT / 4), cv = i % (MT / 4);
        *(float4*)&ws[k * MT + cv * 4] = *(const float4*)&W[k * M + c0 + cv * 4];
    }
    constexpr int KV = K / 4;
    for (int i = tid; i < NODES * KV; i += BLOCK) {
        int r = i / KV, kv = i % KV;
        int node = n0 + r;
        float4 v = make_float4(0.f, 0.f, 0.f, 0.f);
        if (node < N_NODES) v = *(const float4*)&X[(size_t)node * K + kv * 4];
        xs[(kv * 4 + 0) * NODES + r] = v.x;
        xs[(kv * 4 + 1) * NODES + r] = v.y;
        xs[(kv * 4 + 2) * NODES + r] = v.z;
        xs[(kv * 4 + 3) * NODES + r] = v.w;
    }
    __syncthreads();

    const int ft = tid % FTH;
    const int nt = tid / FTH;
    float acc[NT][4];
    #pragma unroll
    for (int i = 0; i < NT; ++i) { acc[i][0] = acc[i][1] = acc[i][2] = acc[i][3] = 0.f; }

    #pragma unroll 4
    for (int k = 0; k < K; ++k) {
        float4 w = *(const float4*)&ws[k * MT + ft * 4];
        float4 xv = *(const float4*)&xs[k * NODES + nt * NT];
        float xa[4] = {xv.x, xv.y, xv.z, xv.w};
        #pragma unroll
        for (int j = 0; j < NT; ++j) {
            acc[j][0] += xa[j] * w.x;
            acc[j][1] += xa[j] * w.y;
            acc[j][2] += xa[j] * w.z;
            acc[j][3] += xa[j] * w.w;
        }
    }
    #pragma unroll
    for (int i = 0; i < NT; ++i) {
        int node = n0 + nt * NT + i;
        if (node < N_NODES) {
            float s = dinv[node];
            float v0 = acc[i][0] * s, v1 = acc[i][1] * s, v2 = acc[i][2] * s, v3 = acc[i][3] * s;
            if constexpr (BF16OUT) {
                unsigned short* H = (unsigned short*)Hv;
                ushort4 o;
                o.x = f2bf(v0); o.y = f2bf(v1); o.z = f2bf(v2); o.w = f2bf(v3);
                *(ushort4*)&H[(size_t)node * OSTRIDE + c0 + ft * 4] = o;
            } else {
                float* H = (float*)Hv;
                *(float4*)&H[(size_t)node * OSTRIDE + c0 + ft * 4] = make_float4(v0, v1, v2, v3);
            }
        }
    }
}

// ---------------- pull aggregation from bf16 H (halved cache-line traffic) ---
// Per-thread chunk of 8 bf16 (one 16B uint4 gather). Gather is MSHR/L3-latency
// bound (~20 G-lines/s ceiling measured r1-r3); bf16 halves lines per row.
template <int F, int STRIDE>
__global__ void k_agg_bf(const unsigned short* __restrict__ H, const int* __restrict__ rs,
                         const int* __restrict__ csr, const float* __restrict__ dinv,
                         const float* __restrict__ bias, float* __restrict__ OUT) {
    constexpr int FV = F / 8;
    int t = blockIdx.x * blockDim.x + threadIdx.x;
    int node = t / FV, c = t % FV;
    if (node >= N_NODES) return;
    int e0 = rs[node], e1 = rs[node + 1];
    const unsigned short* Hc = H + c * 8;
    float a0 = 0.f, a1 = 0.f, a2 = 0.f, a3 = 0.f, a4 = 0.f, a5 = 0.f, a6 = 0.f, a7 = 0.f;
    for (int e = e0; e < e1; ++e) {
        int s = csr[e];
        uint4 v = *(const uint4*)(Hc + (size_t)s * STRIDE);
        a0 += bf_lo(v.x); a1 += bf_hi(v.x);
        a2 += bf_lo(v.y); a3 += bf_hi(v.y);
        a4 += bf_lo(v.z); a5 += bf_hi(v.z);
        a6 += bf_lo(v.w); a7 += bf_hi(v.w);
    }
    float d = dinv[node];
    const float4* bp = (const float4*)(bias + c * 8);
    float4 b0 = bp[0], b1 = bp[1];
    float4 o0, o1;
    o0.x = fmaxf(a0 * d + b0.x, 0.f); o0.y = fmaxf(a1 * d + b0.y, 0.f);
    o0.z = fmaxf(a2 * d + b0.z, 0.f); o0.w = fmaxf(a3 * d + b0.w, 0.f);
    o1.x = fmaxf(a4 * d + b1.x, 0.f); o1.y = fmaxf(a5 * d + b1.y, 0.f);
    o1.z = fmaxf(a6 * d + b1.z, 0.f); o1.w = fmaxf(a7 * d + b1.w, 0.f);
    float* op = OUT + (size_t)node * F + c * 8;
    *(float4*)op = o0;
    *(float4*)(op + 4) = o1;
}

// ---------------- mean-pool per graph (batch sorted -> contiguous ranges) ----
// 64 blocks, one per graph. 256 threads = 8 row-groups x 32 features.
// Coalesced reads, LDS tree reduction, no atomics (r1-r4 lesson: 1.65M
// device-scope atomics onto 8KB cost ~250us in line ping-pong).
__global__ __launch_bounds__(256) void k_pool(const float* __restrict__ H,
                                              const int* __restrict__ start,
                                              float* __restrict__ out) {
    __shared__ float red[256];
    const int g = blockIdx.x;
    const int c = threadIdx.x & 31;
    const int r0 = threadIdx.x >> 5;          // 0..7
    const int lo = start[g], hi = start[g + 1];
    float acc = 0.f;
    for (int r = lo + r0; r < hi; r += 8)
        acc += H[(size_t)r * 32 + c];
    red[threadIdx.x] = acc;
    __syncthreads();
    if (threadIdx.x < 128) red[threadIdx.x] += red[threadIdx.x + 128];
    __syncthreads();
    if (threadIdx.x < 64) red[threadIdx.x] += red[threadIdx.x + 64];
    __syncthreads();
    if (threadIdx.x < 32) {
        float s = red[threadIdx.x] + red[threadIdx.x + 32];
        float cnt = fmaxf((float)(hi - lo), 1.0f);
        out[g * 32 + c] = s / cnt;
    }
}

extern "C" void kernel_launch(void* const* d_in, const int* in_sizes, int n_in,
                              void* d_out, int out_size, void* d_ws, size_t ws_size,
                              hipStream_t stream) {
    const float* x     = (const float*)d_in[0];
    const int*   ei    = (const int*)d_in[1];
    const int*   batch = (const int*)d_in[2];
    const float* W1    = (const float*)d_in[3];
    const float* b1    = (const float*)d_in[4];
    const float* W2    = (const float*)d_in[5];
    const float* b2    = (const float*)d_in[6];
    const float* W3    = (const float*)d_in[7];
    const float* b3    = (const float*)d_in[8];
    float* out = (float*)d_out;

    char* ws = (char*)d_ws;
    size_t o = 0;
    auto alloc = [&](size_t bytes) {
        char* p = ws + o;
        o = (o + bytes + 255) & ~(size_t)255;
        return p;
    };
    // P1: fp32 O1 [50000x96] -> later fp32 O3 [50000x32]
    // P2: bf16 H1 [50000x96] -> later fp32 O2 [50000x48]
    // P3: bf16 H2 [50000x64 pad] -> later bf16 H3 [50000x32]
    float* P1 = (float*)alloc((size_t)N_NODES * 96 * 4);
    char*  P2 = (char*) alloc((size_t)N_NODES * 96 * 2);   // == 48*4
    char*  P3 = (char*) alloc((size_t)N_NODES * 64 * 2);
    int*   deg    = (int*)alloc((size_t)N_NODES * 4);
    float* dinv   = (float*)alloc((size_t)N_NODES * 4);
    int*   rs     = (int*)alloc((size_t)(N_NODES + 1) * 4);
    int*   cursor = (int*)alloc((size_t)N_NODES * 4);
    int*   csr    = (int*)alloc((size_t)E_TOT * 4);
    int*   bsum   = (int*)alloc(64 * 4);
    int*   start  = (int*)alloc((NUM_GRAPHS + 1) * 4);

    unsigned short* H1 = (unsigned short*)P2;   // bf16, stride 96
    float*          O1 = P1;                    // fp32, stride 96
    unsigned short* H2 = (unsigned short*)P3;   // bf16, stride 64 (128B rows)
    float*          O2 = (float*)P2;            // fp32, stride 48
    unsigned short* H3 = (unsigned short*)P3;   // bf16, stride 32 (64B rows)
    float*          O3 = P1;                    // fp32, stride 32

    // build normalization + CSR (by dst) + graph ranges
    hipLaunchKernelGGL(k_init, dim3((N_NODES + 255) / 256), dim3(256), 0, stream, deg);
    hipLaunchKernelGGL(k_deg, dim3((N_EDGES + 255) / 256), dim3(256), 0, stream, ei + N_EDGES, deg);
    hipLaunchKernelGGL(k_scan1, dim3(NB_SCAN), dim3(1024), 0, stream, deg, rs, bsum);
    hipLaunchKernelGGL(k_scan2, dim3(1), dim3(64), 0, stream, bsum);
    hipLaunchKernelGGL(k_scan3, dim3(NB_SCAN), dim3(1024), 0, stream, rs, bsum, cursor, deg, dinv);
    hipLaunchKernelGGL(k_scatter, dim3((E_TOT + 255) / 256), dim3(256), 0, stream, ei, cursor, csr);
    hipLaunchKernelGGL(k_bounds, dim3(1), dim3(128), 0, stream, batch, start);

    // layer 1: K=128 -> M=96, bf16 H
    hipLaunchKernelGGL((k_gemm<128, 96, 48, 12, 16, 4, 96, true>), dim3((N_NODES + 63) / 64, 2), dim3(192), 0, stream,
                       x, W1, dinv, H1);
    hipLaunchKernelGGL((k_agg_bf<96, 96>), dim3((N_NODES * 12 + 255) / 256), dim3(256), 0, stream,
                       H1, rs, csr, dinv, b1, O1);
    // layer 2: K=96 -> M=48, bf16 H padded to 64-elem rows (128B = 2 lines)
    hipLaunchKernelGGL((k_gemm<96, 48, 48, 12, 16, 4, 64, true>), dim3((N_NODES + 63) / 64, 1), dim3(192), 0, stream,
                       O1, W2, dinv, H2);
    hipLaunchKernelGGL((k_agg_bf<48, 64>), dim3((N_NODES * 6 + 255) / 256), dim3(256), 0, stream,
                       H2, rs, csr, dinv, b2, O2);
    // layer 3: K=48 -> M=32, bf16 H (64B rows = exactly 1 line per gather row)
    hipLaunchKernelGGL((k_gemm<48, 32, 32, 8, 24, 4, 32, true>), dim3((N_NODES + 95) / 96, 1), dim3(192), 0, stream,
                       O2, W3, dinv, H3);
    hipLaunchKernelGGL((k_agg_bf<32, 32>), dim3((N_NODES * 4 + 255) / 256), dim3(256), 0, stream,
                       H3, rs, csr, dinv, b3, O3);
    // mean pool over contiguous per-graph node ranges
    hipLaunchKernelGGL(k_pool, dim3(NUM_GRAPHS), dim3(256), 0, stream, O3, start, out);
}

// Round 6
// 342.304 us; speedup vs baseline: 2.3158x; 1.1037x over previous
//
#include <hip/hip_runtime.h>

#define N_NODES 50000
#define N_EDGES 800000
#define NUM_GRAPHS 64
#define NB_SCAN ((N_NODES + 1023) / 1024)   // 49 scan blocks

__device__ __forceinline__ float bf_lo(unsigned u) { return __uint_as_float(u << 16); }
__device__ __forceinline__ float bf_hi(unsigned u) { return __uint_as_float(u & 0xffff0000u); }
__device__ __forceinline__ unsigned short f2bf(float f) {           // RNE
    unsigned u = __float_as_uint(f);
    return (unsigned short)((u + 0x7fffu + ((u >> 16) & 1u)) >> 16);
}

// ---------------- degree histogram (real edges only; self-loop added in dinv) -
__global__ void k_deg(const int* __restrict__ dst, int* __restrict__ deg) {
    int e = blockIdx.x * blockDim.x + threadIdx.x;
    if (e < N_EDGES) atomicAdd(&deg[dst[e]], 1);
}

// ---------------- 3-phase exclusive scan over deg -> row_start ----------------
__global__ __launch_bounds__(1024) void k_scan1(const int* __restrict__ deg,
                                                int* __restrict__ rs,
                                                int* __restrict__ bsum) {
    __shared__ int tmp[1024];
    int tid = threadIdx.x;
    int i = blockIdx.x * 1024 + tid;
    int v = (i < N_NODES) ? deg[i] : 0;
    tmp[tid] = v;
    __syncthreads();
    for (int off = 1; off < 1024; off <<= 1) {
        int add = (tid >= off) ? tmp[tid - off] : 0;
        __syncthreads();
        tmp[tid] += add;
        __syncthreads();
    }
    if (i < N_NODES) rs[i] = tmp[tid] - v;     // block-local exclusive
    if (tid == 1023) bsum[blockIdx.x] = tmp[1023];
}

__global__ void k_scan2(int* __restrict__ bsum) {
    int lane = threadIdx.x;                    // single wave of 64
    int v = (lane < NB_SCAN) ? bsum[lane] : 0;
    int inc = v;
    #pragma unroll
    for (int off = 1; off < 64; off <<= 1) {
        int u = __shfl_up(inc, off, 64);
        if (lane >= off) inc += u;
    }
    if (lane < NB_SCAN) bsum[lane] = inc - v;  // exclusive block offsets
}

__global__ __launch_bounds__(1024) void k_scan3(int* __restrict__ rs,
                                                const int* __restrict__ bsum,
                                                int* __restrict__ cursor,
                                                const int* __restrict__ deg,
                                                float* __restrict__ dinv) {
    int i = blockIdx.x * 1024 + threadIdx.x;
    if (i < N_NODES) {
        int r = rs[i] + bsum[blockIdx.x];
        rs[i] = r;
        cursor[i] = r;
        dinv[i] = rsqrtf((float)(deg[i] + 1));  // +1 = self loop
    }
    if (i == 0) rs[N_NODES] = N_EDGES;
}

// ---------------- CSR scatter (real edges only, uint16 src indices) ----------
// r5 lesson: random 4B stores cost a full 64B line writeback each (54MB for a
// 3.4MB buffer). uint16 halves the line count; self-loops moved to the agg.
__global__ void k_scatter(const int* __restrict__ ei, int* __restrict__ cursor,
                          unsigned short* __restrict__ csr) {
    int e = blockIdx.x * blockDim.x + threadIdx.x;
    if (e >= N_EDGES) return;
    int s = ei[e], d = ei[N_EDGES + e];
    int p = atomicAdd(&cursor[d], 1);
    csr[p] = (unsigned short)s;
}

// ---------------- graph boundaries: start[g] = lower_bound(batch, g) --------
__global__ void k_bounds(const int* __restrict__ batch, int* __restrict__ start) {
    int t = threadIdx.x;
    if (t > NUM_GRAPHS) return;
    int lo = 0, hi = N_NODES;
    while (lo < hi) {
        int mid = (lo + hi) >> 1;
        if (batch[mid] < t) lo = mid + 1; else hi = mid;
    }
    start[t] = lo;
}

// ---------------- GEMM: H[n, :] = (X @ W)[n] * dinv[n], optional bf16 out ----
// W tile in LDS only (<=24.5KB -> 6 blocks/CU); X read straight from global
// (each line reused by FTH threads -> L1 serves it). r5 lesson: the LDS
// X-transpose cost 1.24e7 bank-conflict cycles (32-way on stride-64 stores)
// and its 32KB halved occupancy.
template <int K, int M, int MT, int FTH, int NTH, int NT, int OSTRIDE, bool BF16OUT>
__global__ __launch_bounds__(FTH * NTH)
void k_gemm(const float* __restrict__ X, const float* __restrict__ W,
            const float* __restrict__ dinv, void* __restrict__ Hv) {
    constexpr int BLOCK = FTH * NTH;
    __shared__ float ws[K * MT];
    const int tid = threadIdx.x;
    const int n0 = blockIdx.x * (NTH * NT);
    const int c0 = blockIdx.y * MT;

    for (int i = tid; i < K * MT / 4; i += BLOCK) {
        int k = i / (MT / 4), cv = i % (MT / 4);
        *(float4*)&ws[k * MT + cv * 4] = *(const float4*)&W[k * M + c0 + cv * 4];
    }
    __syncthreads();

    const int ft = tid % FTH;
    const int nt = tid / FTH;
    const float* xp[NT];
    #pragma unroll
    for (int i = 0; i < NT; ++i) {
        int node = n0 + nt * NT + i;
        int nc = node < N_NODES ? node : N_NODES - 1;   // clamp; store is guarded
        xp[i] = X + (size_t)nc * K;
    }
    float acc[NT][4];
    #pragma unroll
    for (int i = 0; i < NT; ++i) { acc[i][0] = acc[i][1] = acc[i][2] = acc[i][3] = 0.f; }

    for (int k = 0; k < K; k += 4) {
        float4 w0 = *(const float4*)&ws[(k + 0) * MT + ft * 4];
        float4 w1 = *(const float4*)&ws[(k + 1) * MT + ft * 4];
        float4 w2 = *(const float4*)&ws[(k + 2) * MT + ft * 4];
        float4 w3 = *(const float4*)&ws[(k + 3) * MT + ft * 4];
        #pragma unroll
        for (int i = 0; i < NT; ++i) {
            float4 xv = *(const float4*)(xp[i] + k);
            acc[i][0] += xv.x * w0.x + xv.y * w1.x + xv.z * w2.x + xv.w * w3.x;
            acc[i][1] += xv.x * w0.y + xv.y * w1.y + xv.z * w2.y + xv.w * w3.y;
            acc[i][2] += xv.x * w0.z + xv.y * w1.z + xv.z * w2.z + xv.w * w3.z;
            acc[i][3] += xv.x * w0.w + xv.y * w1.w + xv.z * w2.w + xv.w * w3.w;
        }
    }
    #pragma unroll
    for (int i = 0; i < NT; ++i) {
        int node = n0 + nt * NT + i;
        if (node < N_NODES) {
            float s = dinv[node];
            float v0 = acc[i][0] * s, v1 = acc[i][1] * s, v2 = acc[i][2] * s, v3 = acc[i][3] * s;
            if constexpr (BF16OUT) {
                unsigned short* H = (unsigned short*)Hv;
                ushort4 o;
                o.x = f2bf(v0); o.y = f2bf(v1); o.z = f2bf(v2); o.w = f2bf(v3);
                *(ushort4*)&H[(size_t)node * OSTRIDE + c0 + ft * 4] = o;
            } else {
                float* H = (float*)Hv;
                *(float4*)&H[(size_t)node * OSTRIDE + c0 + ft * 4] = make_float4(v0, v1, v2, v3);
            }
        }
    }
}

// ---------------- pull aggregation from bf16 H (halved cache-line traffic) ---
// Per-thread chunk of 8 bf16 (one 16B uint4 gather). Self-loop term read
// directly from own row (L1-hit; not stored in CSR).
template <int F, int STRIDE>
__global__ void k_agg_bf(const unsigned short* __restrict__ H, const int* __restrict__ rs,
                         const unsigned short* __restrict__ csr, const float* __restrict__ dinv,
                         const float* __restrict__ bias, float* __restrict__ OUT) {
    constexpr int FV = F / 8;
    int t = blockIdx.x * blockDim.x + threadIdx.x;
    int node = t / FV, c = t % FV;
    if (node >= N_NODES) return;
    int e0 = rs[node], e1 = rs[node + 1];
    const unsigned short* Hc = H + c * 8;
    uint4 sv = *(const uint4*)(Hc + (size_t)node * STRIDE);   // self loop
    float a0 = bf_lo(sv.x), a1 = bf_hi(sv.x), a2 = bf_lo(sv.y), a3 = bf_hi(sv.y);
    float a4 = bf_lo(sv.z), a5 = bf_hi(sv.z), a6 = bf_lo(sv.w), a7 = bf_hi(sv.w);
    for (int e = e0; e < e1; ++e) {
        int s = csr[e];
        uint4 v = *(const uint4*)(Hc + (size_t)s * STRIDE);
        a0 += bf_lo(v.x); a1 += bf_hi(v.x);
        a2 += bf_lo(v.y); a3 += bf_hi(v.y);
        a4 += bf_lo(v.z); a5 += bf_hi(v.z);
        a6 += bf_lo(v.w); a7 += bf_hi(v.w);
    }
    float d = dinv[node];
    const float4* bp = (const float4*)(bias + c * 8);
    float4 b0 = bp[0], b1 = bp[1];
    float4 o0, o1;
    o0.x = fmaxf(a0 * d + b0.x, 0.f); o0.y = fmaxf(a1 * d + b0.y, 0.f);
    o0.z = fmaxf(a2 * d + b0.z, 0.f); o0.w = fmaxf(a3 * d + b0.w, 0.f);
    o1.x = fmaxf(a4 * d + b1.x, 0.f); o1.y = fmaxf(a5 * d + b1.y, 0.f);
    o1.z = fmaxf(a6 * d + b1.z, 0.f); o1.w = fmaxf(a7 * d + b1.w, 0.f);
    float* op = OUT + (size_t)node * F + c * 8;
    *(float4*)op = o0;
    *(float4*)(op + 4) = o1;
}

// ---------------- mean-pool per graph (batch sorted -> contiguous ranges) ----
__global__ __launch_bounds__(256) void k_pool(const float* __restrict__ H,
                                              const int* __restrict__ start,
                                              float* __restrict__ out) {
    __shared__ float red[256];
    const int g = blockIdx.x;
    const int c = threadIdx.x & 31;
    const int r0 = threadIdx.x >> 5;          // 0..7
    const int lo = start[g], hi = start[g + 1];
    float acc = 0.f;
    for (int r = lo + r0; r < hi; r += 8)
        acc += H[(size_t)r * 32 + c];
    red[threadIdx.x] = acc;
    __syncthreads();
    if (threadIdx.x < 128) red[threadIdx.x] += red[threadIdx.x + 128];
    __syncthreads();
    if (threadIdx.x < 64) red[threadIdx.x] += red[threadIdx.x + 64];
    __syncthreads();
    if (threadIdx.x < 32) {
        float s = red[threadIdx.x] + red[threadIdx.x + 32];
        float cnt = fmaxf((float)(hi - lo), 1.0f);
        out[g * 32 + c] = s / cnt;
    }
}

extern "C" void kernel_launch(void* const* d_in, const int* in_sizes, int n_in,
                              void* d_out, int out_size, void* d_ws, size_t ws_size,
                              hipStream_t stream) {
    const float* x     = (const float*)d_in[0];
    const int*   ei    = (const int*)d_in[1];
    const int*   batch = (const int*)d_in[2];
    const float* W1    = (const float*)d_in[3];
    const float* b1    = (const float*)d_in[4];
    const float* W2    = (const float*)d_in[5];
    const float* b2    = (const float*)d_in[6];
    const float* W3    = (const float*)d_in[7];
    const float* b3    = (const float*)d_in[8];
    float* out = (float*)d_out;

    char* ws = (char*)d_ws;
    size_t o = 0;
    auto alloc = [&](size_t bytes) {
        char* p = ws + o;
        o = (o + bytes + 255) & ~(size_t)255;
        return p;
    };
    // P1: fp32 O1 [50000x96] -> later fp32 O3 [50000x32]
    // P2: bf16 H1 [50000x96] -> later fp32 O2 [50000x48]
    // P3: bf16 H2 [50000x64 pad] -> later bf16 H3 [50000x32]
    float* P1 = (float*)alloc((size_t)N_NODES * 96 * 4);
    char*  P2 = (char*) alloc((size_t)N_NODES * 96 * 2);   // == 48*4
    char*  P3 = (char*) alloc((size_t)N_NODES * 64 * 2);
    int*   deg    = (int*)alloc((size_t)N_NODES * 4);
    float* dinv   = (float*)alloc((size_t)N_NODES * 4);
    int*   rs     = (int*)alloc((size_t)(N_NODES + 1) * 4);
    int*   cursor = (int*)alloc((size_t)N_NODES * 4);
    unsigned short* csr = (unsigned short*)alloc((size_t)N_EDGES * 2);
    int*   bsum   = (int*)alloc(64 * 4);
    int*   start  = (int*)alloc((NUM_GRAPHS + 1) * 4);

    unsigned short* H1 = (unsigned short*)P2;   // bf16, stride 96
    float*          O1 = P1;                    // fp32, stride 96
    unsigned short* H2 = (unsigned short*)P3;   // bf16, stride 64 (128B rows)
    float*          O2 = (float*)P2;            // fp32, stride 48
    unsigned short* H3 = (unsigned short*)P3;   // bf16, stride 32 (64B rows)
    float*          O3 = P1;                    // fp32, stride 32

    // build normalization + CSR (by dst) + graph ranges
    hipMemsetAsync(deg, 0, (size_t)N_NODES * 4, stream);
    hipLaunchKernelGGL(k_deg, dim3((N_EDGES + 255) / 256), dim3(256), 0, stream, ei + N_EDGES, deg);
    hipLaunchKernelGGL(k_scan1, dim3(NB_SCAN), dim3(1024), 0, stream, deg, rs, bsum);
    hipLaunchKernelGGL(k_scan2, dim3(1), dim3(64), 0, stream, bsum);
    hipLaunchKernelGGL(k_scan3, dim3(NB_SCAN), dim3(1024), 0, stream, rs, bsum, cursor, deg, dinv);
    hipLaunchKernelGGL(k_scatter, dim3((N_EDGES + 255) / 256), dim3(256), 0, stream, ei, cursor, csr);
    hipLaunchKernelGGL(k_bounds, dim3(1), dim3(128), 0, stream, batch, start);

    // layer 1: K=128 -> M=96 (two 48-wide tiles), bf16 H
    hipLaunchKernelGGL((k_gemm<128, 96, 48, 12, 16, 4, 96, true>), dim3((N_NODES + 63) / 64, 2), dim3(192), 0, stream,
                       x, W1, dinv, H1);
    hipLaunchKernelGGL((k_agg_bf<96, 96>), dim3((N_NODES * 12 + 255) / 256), dim3(256), 0, stream,
                       H1, rs, csr, dinv, b1, O1);
    // layer 2: K=96 -> M=48, bf16 H padded to 64-elem rows (128B = 2 lines)
    hipLaunchKernelGGL((k_gemm<96, 48, 48, 12, 16, 4, 64, true>), dim3((N_NODES + 63) / 64, 1), dim3(192), 0, stream,
                       O1, W2, dinv, H2);
    hipLaunchKernelGGL((k_agg_bf<48, 64>), dim3((N_NODES * 6 + 255) / 256), dim3(256), 0, stream,
                       H2, rs, csr, dinv, b2, O2);
    // layer 3: K=48 -> M=32, bf16 H (64B rows = exactly 1 line per gather row)
    hipLaunchKernelGGL((k_gemm<48, 32, 32, 8, 24, 4, 32, true>), dim3((N_NODES + 95) / 96, 1), dim3(192), 0, stream,
                       O2, W3, dinv, H3);
    hipLaunchKernelGGL((k_agg_bf<32, 32>), dim3((N_NODES * 4 + 255) / 256), dim3(256), 0, stream,
                       H3, rs, csr, dinv, b3, O3);
    // mean pool over contiguous per-graph node ranges
    hipLaunchKernelGGL(k_pool, dim3(NUM_GRAPHS), dim3(256), 0, stream, O3, start, out);
}